// Round 10
// baseline (276.345 us; speedup 1.0000x reference)
//
#include <hip/hip_runtime.h>

// GCN_72971494359045: 2-layer GCNConv(+self-loops, sym-norm) with PReLU.
// N=50000 nodes, E=800000 edges, dims 128(+8 id)->256->128, all fp32.
//
// R9: launch-count 11 -> 8: prep_weights fused into tile_count;
// bucket_base scan inlined (LDS) into scatter & csr; scale_x fused into
// bucket_csr; svec fused into agg1 as extra blocks. h1 stored as plain
// bf16 (gemm1 -25.6 MB write, gemm2 -25.6 MB read and 2 MFMA/tile).

constexpr int NN = 50000;
constexpr int NE = 800000;
constexpr int NBUCK = 196;   // ceil(NN / 256), bucket = dst >> 8
constexpr int TILE = 2048;   // edges per scatter block
constexpr int NSCAT = (NE + TILE - 1) / TILE;  // 391
constexpr int NAGG = NN / 4; // agg blocks (4 waves x 1 node)

typedef __attribute__((ext_vector_type(8))) short short8;
typedef __attribute__((ext_vector_type(4))) float floatx4;

__device__ inline void bsplit(float v, unsigned short& hi, unsigned short& lo) {
  unsigned u = __float_as_uint(v);
  hi = (unsigned short)(u >> 16);
  float rem = v - __uint_as_float(u & 0xffff0000u);
  lo = (unsigned short)(__float_as_uint(rem) >> 16);
}

__device__ inline unsigned short bf16_rtne(float v) {
  unsigned u = __float_as_uint(v);
  return (unsigned short)((u + 0x7fffu + ((u >> 16) & 1u)) >> 16);
}

__device__ inline float bflo(unsigned u) { return __uint_as_float(u << 16); }
__device__ inline float bfhi(unsigned u) { return __uint_as_float(u & 0xffff0000u); }

// Pack W[K x N] (fp32, row-major) into MFMA B-fragment order, split hi/lo.
template <int K, int N>
__device__ inline void pack_one(const float* __restrict__ W, unsigned short* __restrict__ Bhi,
                                unsigned short* __restrict__ Blo, int id) {
  constexpr int KC = K / 32;
  int j = id & 7;
  int lane = (id >> 3) & 63;
  int rest = id >> 9;
  int c = rest % KC;
  int nt = rest / KC;
  int k = c * 32 + (lane >> 4) * 8 + j;
  int n = nt * 16 + (lane & 15);
  unsigned short hi, lo;
  bsplit(W[(size_t)k * N + n], hi, lo);
  Bhi[id] = hi;
  Blo[id] = lo;
}

// Fused: per-tile bucket histogram (blocks < NSCAT) + weight prep (rest).
__global__ __launch_bounds__(256) void front_kernel(
    const int* __restrict__ ei, int* __restrict__ tilecnt,
    const float* __restrict__ W1, const float* __restrict__ W2,
    const float* __restrict__ idv,
    unsigned short* __restrict__ B1hi, unsigned short* __restrict__ B1lo,
    unsigned short* __restrict__ B2hi, unsigned short* __restrict__ B2lo,
    float* __restrict__ cvec) {
  int t = threadIdx.x;
  if (blockIdx.x < NSCAT) {
    __shared__ int h[NBUCK];
    for (int i = t; i < NBUCK; i += 256) h[i] = 0;
    __syncthreads();
    int base = blockIdx.x * TILE;
    int end = base + TILE; if (end > NE) end = NE;
    for (int e = base + t; e < end; e += 256) atomicAdd(&h[ei[NE + e] >> 8], 1);
    __syncthreads();
    for (int i = t; i < NBUCK; i += 256) tilecnt[blockIdx.x * NBUCK + i] = h[i];
  } else {
    int id = (blockIdx.x - NSCAT) * 256 + t;
    if (id < 32768) {
      pack_one<128, 256>(W1, B1hi, B1lo, id);
    } else if (id < 65536) {
      pack_one<256, 128>(W2, B2hi, B2lo, id - 32768);
    } else if (id < 65536 + 256) {
      int m = id - 65536;
      float c = 0.f;
#pragma unroll
      for (int j = 0; j < 8; ++j) c += idv[j] * W1[(128 + j) * 256 + m];
      cvec[m] = c;
    }
  }
}

// One block per bucket: exclusive scan of its count across the 391 tiles.
__global__ __launch_bounds__(256) void tile_scan_a_kernel(const int* __restrict__ tilecnt,
                                                          int* __restrict__ tpre,
                                                          int* __restrict__ bcnt) {
  __shared__ int sm[256];
  int b = blockIdx.x, t = threadIdx.x;
  int i0 = 2 * t, i1 = 2 * t + 1;
  int v0 = (i0 < NSCAT) ? tilecnt[i0 * NBUCK + b] : 0;
  int v1 = (i1 < NSCAT) ? tilecnt[i1 * NBUCK + b] : 0;
  int s = v0 + v1;
  sm[t] = s;
  __syncthreads();
  for (int off = 1; off < 256; off <<= 1) {
    int u = (t >= off) ? sm[t - off] : 0;
    __syncthreads();
    sm[t] += u;
    __syncthreads();
  }
  int ex = sm[t] - s;
  if (i0 < NSCAT) tpre[i0 * NBUCK + b] = ex;
  if (i1 < NSCAT) tpre[i1 * NBUCK + b] = ex + v0;
  if (t == 255) bcnt[b] = sm[255];
}

// Stage tile in LDS grouped by bucket; flush in parallel (binary search
// for owning bucket). Bucket bases computed by an inline LDS scan of bcnt.
// val = (dst&255)<<16 | src (src < 65536).
__global__ __launch_bounds__(256) void bucket_scatter_kernel(
    const int* __restrict__ ei, const int* __restrict__ tilecnt,
    const int* __restrict__ tpre, const int* __restrict__ bcnt,
    unsigned* __restrict__ ebuf) {
  __shared__ int lbase[NBUCK], gb[NBUCK], lcur[NBUCK], ssc[256], bscan[256];
  __shared__ unsigned stage[TILE];
  int t = threadIdx.x;
  int tile = blockIdx.x;
  int base = tile * TILE;
  int cntTile = NE - base; if (cntTile > TILE) cntTile = TILE;
  // bucket bases from bcnt (exclusive scan)
  int bv = (t < NBUCK) ? bcnt[t] : 0;
  bscan[t] = bv;
  // tile-local histogram scan
  int h = (t < NBUCK) ? tilecnt[tile * NBUCK + t] : 0;
  ssc[t] = h;
  __syncthreads();
  for (int off = 1; off < 256; off <<= 1) {
    int u1 = (t >= off) ? ssc[t - off] : 0;
    int u2 = (t >= off) ? bscan[t - off] : 0;
    __syncthreads();
    ssc[t] += u1;
    bscan[t] += u2;
    __syncthreads();
  }
  if (t < NBUCK) {
    int ex = ssc[t] - h;
    lbase[t] = ex;
    lcur[t] = ex;
    gb[t] = (bscan[t] - bv) + tpre[tile * NBUCK + t];
  }
  __syncthreads();
  for (int e = base + t; e < base + cntTile; e += 256) {
    int s = ei[e];
    int d = ei[NE + e];
    int b = d >> 8;
    int pos = atomicAdd(&lcur[b], 1);
    stage[pos] = ((unsigned)(d & 255) << 16) | (unsigned)s;
  }
  __syncthreads();
  for (int i = t; i < cntTile; i += 256) {
    int lo = 0, hi = NBUCK - 1;
    while (lo < hi) {
      int mid = (lo + hi + 1) >> 1;
      if (lbase[mid] <= i) lo = mid; else hi = mid - 1;
    }
    ebuf[gb[lo] + (i - lbase[lo])] = stage[i];
  }
}

// One block per bucket (256 nodes): node histogram -> offs/dinv, col
// scatter into the bucket's contiguous L2 window, + fused x-scale to bf16.
__global__ __launch_bounds__(256) void bucket_csr_kernel(
    const unsigned* __restrict__ ebuf, const int* __restrict__ bcnt,
    const float* __restrict__ x,
    int* __restrict__ offs, int* __restrict__ col,
    float* __restrict__ dinv, unsigned short* __restrict__ xsb) {
  __shared__ int cnt[256], cur[256], sums[256], bscan[256];
  __shared__ float dinvs[256];
  __shared__ int g0s;
  int b = blockIdx.x, t = threadIdx.x;
  int node0 = b << 8;
  cnt[t] = 0;
  int bv = (t < NBUCK) ? bcnt[t] : 0;
  bscan[t] = bv;
  __syncthreads();
  for (int off = 1; off < 256; off <<= 1) {
    int u = (t >= off) ? bscan[t - off] : 0;
    __syncthreads();
    bscan[t] += u;
    __syncthreads();
  }
  if (t == b) g0s = bscan[t] - bv;  // this bucket's base
  __syncthreads();
  int g0 = g0s, g1 = g0 + bcnt[b];
  for (int i = g0 + t; i < g1; i += 256) atomicAdd(&cnt[ebuf[i] >> 16], 1);
  __syncthreads();
  int c = cnt[t];
  sums[t] = c;
  __syncthreads();
  for (int off = 1; off < 256; off <<= 1) {
    int u = (t >= off) ? sums[t - off] : 0;
    __syncthreads();
    sums[t] += u;
    __syncthreads();
  }
  int ex = sums[t] - c;
  cur[t] = ex;
  float dval = rsqrtf((float)(c + 1));
  dinvs[t] = dval;
  int node = node0 + t;
  if (node < NN) {
    offs[node] = g0 + ex;
    dinv[node] = dval;
  }
  __syncthreads();
  for (int i = g0 + t; i < g1; i += 256) {
    unsigned v = ebuf[i];
    int pos = atomicAdd(&cur[v >> 16], 1);
    col[g0 + pos] = (int)(v & 0xffffu);
  }
  // fused: xsb[n,:] = bf16(x[n,:] * dinv[n]) for this bucket's nodes
  for (int i = t; i < 256 * 32; i += 256) {
    int ln = i >> 5;
    int n2 = node0 + ln;
    if (n2 >= NN) continue;
    float dd = dinvs[ln];
    float4 v = ((const float4*)x)[(size_t)n2 * 32 + (i & 31)];
    ushort4 o;
    o.x = bf16_rtne(v.x * dd);
    o.y = bf16_rtne(v.y * dd);
    o.z = bf16_rtne(v.z * dd);
    o.w = bf16_rtne(v.w * dd);
    ((ushort4*)xsb)[(size_t)n2 * 32 + (i & 31)] = o;
  }
  if (b == 0 && t == 0) offs[NN] = NE;
}

// Wave per node; 32 lanes x 4 bf16 (uint2) cover the 128-wide row; two
// 32-lane halves take alternating edges; main tier = 8 edges/half
// (16 row-loads in flight per wave), then 2- and 1-edge tails.
// MODE 0 (layer1): out = dd*(self+sum) -> split bf16 hi/lo; extra blocks
//                  (>= NAGG) compute Svec[d] = dd*(dd + sum dinv[s]).
// MODE 1 (layer2): out = prelu(dd*(self+sum)+b, a) -> fp32 final output.
template <int MODE>
__global__ __launch_bounds__(256) void agg_kernel(
    const unsigned short* __restrict__ in, const float* __restrict__ dinv,
    const int* __restrict__ offs, const int* __restrict__ col,
    const float* __restrict__ bias, const float* __restrict__ alpha,
    unsigned short* __restrict__ outhi, unsigned short* __restrict__ outlo,
    float* __restrict__ outf, float* __restrict__ Svec) {
  int t = threadIdx.x;
  if (MODE == 0 && blockIdx.x >= NAGG) {  // fused svec tail blocks
    int d = (blockIdx.x - NAGG) * 256 + t;
    if (d < NN) {
      float s = 0.f;
      int end = offs[d + 1];
      for (int p = offs[d]; p < end; ++p) s += dinv[col[p]];
      float dd = dinv[d];
      Svec[d] = dd * (dd + s);
    }
    return;
  }
  const uint2* inb = (const uint2*)in;  // row = 32 uint2 (128 bf16)
  int node = blockIdx.x * 4 + (t >> 6);
  int lane = t & 63;
  int r = lane & 31;
  int half = lane >> 5;
  int beg = offs[node], end = offs[node + 1];

  float4 a0 = make_float4(0.f, 0.f, 0.f, 0.f);
  float4 a1 = make_float4(0.f, 0.f, 0.f, 0.f);
  float4 a2 = make_float4(0.f, 0.f, 0.f, 0.f);
  float4 a3 = make_float4(0.f, 0.f, 0.f, 0.f);
  int p = beg + half;
  for (; p + 14 < end; p += 16) {  // 8 edges per half-wave
    int s0 = col[p];      int s1 = col[p + 2];
    int s2 = col[p + 4];  int s3 = col[p + 6];
    int s4 = col[p + 8];  int s5 = col[p + 10];
    int s6 = col[p + 12]; int s7 = col[p + 14];
    uint2 v0 = inb[(size_t)s0 * 32 + r];
    uint2 v1 = inb[(size_t)s1 * 32 + r];
    uint2 v2 = inb[(size_t)s2 * 32 + r];
    uint2 v3 = inb[(size_t)s3 * 32 + r];
    uint2 v4 = inb[(size_t)s4 * 32 + r];
    uint2 v5 = inb[(size_t)s5 * 32 + r];
    uint2 v6 = inb[(size_t)s6 * 32 + r];
    uint2 v7 = inb[(size_t)s7 * 32 + r];
    a0.x += bflo(v0.x); a0.y += bfhi(v0.x); a0.z += bflo(v0.y); a0.w += bfhi(v0.y);
    a1.x += bflo(v1.x); a1.y += bfhi(v1.x); a1.z += bflo(v1.y); a1.w += bfhi(v1.y);
    a2.x += bflo(v2.x); a2.y += bfhi(v2.x); a2.z += bflo(v2.y); a2.w += bfhi(v2.y);
    a3.x += bflo(v3.x); a3.y += bfhi(v3.x); a3.z += bflo(v3.y); a3.w += bfhi(v3.y);
    a0.x += bflo(v4.x); a0.y += bfhi(v4.x); a0.z += bflo(v4.y); a0.w += bfhi(v4.y);
    a1.x += bflo(v5.x); a1.y += bfhi(v5.x); a1.z += bflo(v5.y); a1.w += bfhi(v5.y);
    a2.x += bflo(v6.x); a2.y += bfhi(v6.x); a2.z += bflo(v6.y); a2.w += bfhi(v6.y);
    a3.x += bflo(v7.x); a3.y += bfhi(v7.x); a3.z += bflo(v7.y); a3.w += bfhi(v7.y);
  }
  for (; p + 2 < end; p += 4) {  // 2 edges
    int s0 = col[p];
    int s1 = col[p + 2];
    uint2 v0 = inb[(size_t)s0 * 32 + r];
    uint2 v1 = inb[(size_t)s1 * 32 + r];
    a0.x += bflo(v0.x); a0.y += bfhi(v0.x); a0.z += bflo(v0.y); a0.w += bfhi(v0.y);
    a1.x += bflo(v1.x); a1.y += bfhi(v1.x); a1.z += bflo(v1.y); a1.w += bfhi(v1.y);
  }
  if (p < end) {
    uint2 v0 = inb[(size_t)col[p] * 32 + r];
    a0.x += bflo(v0.x); a0.y += bfhi(v0.x); a0.z += bflo(v0.y); a0.w += bfhi(v0.y);
  }
  float4 acc = make_float4((a0.x + a1.x) + (a2.x + a3.x), (a0.y + a1.y) + (a2.y + a3.y),
                           (a0.z + a1.z) + (a2.z + a3.z), (a0.w + a1.w) + (a2.w + a3.w));
  acc.x += __shfl_xor(acc.x, 32);
  acc.y += __shfl_xor(acc.y, 32);
  acc.z += __shfl_xor(acc.z, 32);
  acc.w += __shfl_xor(acc.w, 32);

  float dd = dinv[node];
  if (half == 0) {
    uint2 sv = inb[(size_t)node * 32 + r];
    acc.x = dd * (acc.x + bflo(sv.x));
    acc.y = dd * (acc.y + bfhi(sv.x));
    acc.z = dd * (acc.z + bflo(sv.y));
    acc.w = dd * (acc.w + bfhi(sv.y));
    if (MODE == 0) {
      ushort4 h4, l4;
      bsplit(acc.x, h4.x, l4.x);
      bsplit(acc.y, h4.y, l4.y);
      bsplit(acc.z, h4.z, l4.z);
      bsplit(acc.w, h4.w, l4.w);
      ((ushort4*)outhi)[(size_t)node * 32 + r] = h4;
      ((ushort4*)outlo)[(size_t)node * 32 + r] = l4;
    } else {
      float4 b = ((const float4*)bias)[r];
      float4 al = ((const float4*)alpha)[r];
      acc.x += b.x; acc.y += b.y; acc.z += b.z; acc.w += b.w;
      acc.x = (acc.x >= 0.f) ? acc.x : al.x * acc.x;
      acc.y = (acc.y >= 0.f) ? acc.y : al.y * acc.y;
      acc.z = (acc.z >= 0.f) ? acc.z : al.z * acc.z;
      acc.w = (acc.w >= 0.f) ? acc.w : al.w * acc.w;
      ((float4*)outf)[(size_t)node * 32 + r] = acc;
    }
  }
}

// Split/plain-bf16 MFMA GEMM: C = A @ (Bhi+Blo) [+ A-lo term if ASPLIT].
// MODE 1: v = prelu(acc + Svec[r]*cvec[c] + bias[c], alpha[c]) -> Cb bf16.
// MODE 2: v = acc * rowscale[r] -> Cb bf16 (feeds the layer-2 gather).
template <int K, int N, int MODE, int ASPLIT>
__global__ __launch_bounds__(256) void gemm_mfma_kernel(
    const unsigned short* __restrict__ Ahi, const unsigned short* __restrict__ Alo,
    const unsigned short* __restrict__ Bhi, const unsigned short* __restrict__ Blo,
    const float* __restrict__ Svec, const float* __restrict__ cvec,
    const float* __restrict__ bias, const float* __restrict__ alpha,
    const float* __restrict__ rowscale, unsigned short* __restrict__ Cb) {
  constexpr int KC = K / 32;
  constexpr int NT = N / 16;
  int wave = threadIdx.x >> 6;
  int lane = threadIdx.x & 63;
  int row0 = blockIdx.x * 64 + wave * 16;
  if (row0 >= NN) return;
  int m = lane & 15, quad = lane >> 4;
  int arow = row0 + m;

  short8 ah[KC], al[KC];
  const unsigned short* ap = Ahi + (size_t)arow * K + quad * 8;
#pragma unroll
  for (int c = 0; c < KC; ++c) ah[c] = *(const short8*)(ap + c * 32);
  if (ASPLIT) {
    const unsigned short* alp = Alo + (size_t)arow * K + quad * 8;
#pragma unroll
    for (int c = 0; c < KC; ++c) al[c] = *(const short8*)(alp + c * 32);
  }

  float sv[4];
#pragma unroll
  for (int i = 0; i < 4; ++i) {
    int r = row0 + quad * 4 + i;
    sv[i] = (MODE == 1) ? Svec[r] : rowscale[r];
  }

#pragma unroll 1
  for (int nt = 0; nt < NT; ++nt) {
    floatx4 acc = {0.f, 0.f, 0.f, 0.f};
#pragma unroll
    for (int c = 0; c < KC; ++c) {
      short8 bh = *(const short8*)(Bhi + ((size_t)(nt * KC + c) * 64 + lane) * 8);
      short8 bl = *(const short8*)(Blo + ((size_t)(nt * KC + c) * 64 + lane) * 8);
      acc = __builtin_amdgcn_mfma_f32_16x16x32_bf16(ah[c], bh, acc, 0, 0, 0);
      acc = __builtin_amdgcn_mfma_f32_16x16x32_bf16(ah[c], bl, acc, 0, 0, 0);
      if (ASPLIT) acc = __builtin_amdgcn_mfma_f32_16x16x32_bf16(al[c], bh, acc, 0, 0, 0);
    }
    int c0 = nt * 16 + m;
    if (MODE == 1) {
      float cv = cvec[c0], bb = bias[c0], aa = alpha[c0];
#pragma unroll
      for (int i = 0; i < 4; ++i) {
        int r = row0 + quad * 4 + i;
        float v = acc[i] + sv[i] * cv + bb;
        v = (v >= 0.f) ? v : aa * v;
        Cb[(size_t)r * N + c0] = bf16_rtne(v);
      }
    } else {
#pragma unroll
      for (int i = 0; i < 4; ++i) {
        int r = row0 + quad * 4 + i;
        Cb[(size_t)r * N + c0] = bf16_rtne(acc[i] * sv[i]);
      }
    }
  }
}

extern "C" void kernel_launch(void* const* d_in, const int* in_sizes, int n_in,
                              void* d_out, int out_size, void* d_ws, size_t ws_size,
                              hipStream_t stream) {
  const float* x = (const float*)d_in[0];
  const int* ei = (const int*)d_in[1];
  const float* idv = (const float*)d_in[2];
  const float* W1 = (const float*)d_in[3];
  const float* b1 = (const float*)d_in[4];
  const float* a1 = (const float*)d_in[5];
  const float* W2 = (const float*)d_in[6];
  const float* b2 = (const float*)d_in[7];
  const float* a2 = (const float*)d_in[8];
  float* out = (float*)d_out;

  char* w = (char*)d_ws;
  size_t off = 0;
  auto alloc = [&](size_t bytes) -> void* {
    void* p = w + off;
    off += bytes;
    off = (off + 255) & ~(size_t)255;
    return p;
  };
  int* tilecnt = (int*)alloc((size_t)NSCAT * NBUCK * 4);
  int* tpre = (int*)alloc((size_t)NSCAT * NBUCK * 4);
  int* bcnt = (int*)alloc((size_t)NBUCK * 4);
  unsigned* ebuf = (unsigned*)alloc((size_t)NE * 4);
  float* dinv = (float*)alloc((size_t)NN * 4);
  float* Svec = (float*)alloc((size_t)NN * 4);
  int* offs = (int*)alloc((size_t)(NN + 1) * 4);
  int* col = (int*)alloc((size_t)NE * 4);
  float* cvec = (float*)alloc(256 * 4);
  unsigned short* xsb = (unsigned short*)alloc((size_t)NN * 128 * 2);
  unsigned short* aggxhi = (unsigned short*)alloc((size_t)NN * 128 * 2);
  unsigned short* aggxlo = (unsigned short*)alloc((size_t)NN * 128 * 2);
  unsigned short* h1b = (unsigned short*)alloc((size_t)NN * 256 * 2);
  unsigned short* h2b = (unsigned short*)alloc((size_t)NN * 128 * 2);
  unsigned short* B1hi = (unsigned short*)alloc(128 * 256 * 2);
  unsigned short* B1lo = (unsigned short*)alloc(128 * 256 * 2);
  unsigned short* B2hi = (unsigned short*)alloc(256 * 128 * 2);
  unsigned short* B2lo = (unsigned short*)alloc(256 * 128 * 2);

  // 1. tile histograms + weight prep (independent, fused)
  front_kernel<<<NSCAT + 257, 256, 0, stream>>>(ei, tilecnt, W1, W2, idv,
                                                B1hi, B1lo, B2hi, B2lo, cvec);
  // 2. per-bucket tile prefix sums + bucket totals
  tile_scan_a_kernel<<<NBUCK, 256, 0, stream>>>(tilecnt, tpre, bcnt);
  // 3. radix partition into per-bucket windows
  bucket_scatter_kernel<<<NSCAT, 256, 0, stream>>>(ei, tilecnt, tpre, bcnt, ebuf);
  // 4. per-bucket CSR + dinv + fused x-scale to bf16
  bucket_csr_kernel<<<NBUCK, 256, 0, stream>>>(ebuf, bcnt, x, offs, col, dinv, xsb);
  // 5. layer-1 aggregate -> split bf16 hi/lo; tail blocks compute Svec
  agg_kernel<0><<<NAGG + NBUCK, 256, 0, stream>>>(xsb, dinv, offs, col, nullptr, nullptr,
                                                  aggxhi, aggxlo, nullptr, Svec);
  // 6. h1 = prelu(aggx@W1 + Svec*cvec + b1) -> plain bf16
  gemm_mfma_kernel<128, 256, 1, 1><<<(NN + 63) / 64, 256, 0, stream>>>(
      aggxhi, aggxlo, B1hi, B1lo, Svec, cvec, b1, a1, nullptr, h1b);
  // 7. h2b = bf16((h1@W2) * dinv[row]) -- plain-bf16 A, 2 MFMA/tile
  gemm_mfma_kernel<256, 128, 2, 0><<<(NN + 63) / 64, 256, 0, stream>>>(
      h1b, nullptr, B2hi, B2lo, nullptr, nullptr, nullptr, nullptr, dinv, h2b);
  // 8. layer-2 aggregate + bias + prelu -> fp32 out
  agg_kernel<1><<<NAGG, 256, 0, stream>>>(h2b, dinv, offs, col, b2, a2,
                                          nullptr, nullptr, out, nullptr);
}